// Round 3
// baseline (1517.762 us; speedup 1.0000x reference)
//
#include <hip/hip_runtime.h>

#define N_NODES 131072
#define C_DIM   128
#define H_DIM   128
#define B_SEG   1024
#define M_TILE  128
#define KT      16          // K-tile (channels per iteration)
#define NTILES  8           // C_DIM / KT
#define ROWSTR  132         // LDS row stride (floats): 16B-aligned, permute-friendly
#define TILE_F  (KT * ROWSTR)   // 2112 floats per buffer
#define SEGCAP  384

// ---------------------------------------------------------------------------
// Kernel 1: v[n] = lin(n) + relu(x3 @ W1 + b1) @ W2 + b2
// 1-barrier-per-iter software pipeline, double-buffered Yt & W1s.
// W1s stored group-permuted: float4-group g -> g + (g>>4)  => both W-side
// b128 reads are 2-way bank aliased (free); Y-side reads are broadcast.
// ---------------------------------------------------------------------------
__global__ __launch_bounds__(256, 3)
void node_readout_kernel(const float* __restrict__ emb,
                         const float* __restrict__ W_lins,
                         const float* __restrict__ b_lins,
                         const float* __restrict__ W1,
                         const float* __restrict__ b1,
                         const float* __restrict__ W2,
                         const float* __restrict__ b2,
                         float* __restrict__ v_out)
{
    __shared__ float smem[4 * TILE_F];   // Yt0 | Yt1 | Ws0 | Ws1  = 33.8 KB
    __shared__ float WLs[3 * C_DIM];     // 1.5 KB
    __shared__ float lin_lds[M_TILE];    // 0.5 KB

    const int t     = threadIdx.x;
    const int nbase = blockIdx.x * M_TILE;
    const int cc    = t & 15;    // loader: channel-f4 within tile
    const int ln    = t >> 4;    // loader: node sub-index (0..15)
    const int jg    = t & 15;    // gemm: j-group (8 j's, contiguous)
    const int mg    = t >> 4;    // gemm: m-group (8 m's, contiguous)

    for (int i = t; i < 3 * C_DIM; i += 256) WLs[i] = W_lins[i];

    float acc[8][8];
    #pragma unroll
    for (int mi = 0; mi < 8; ++mi)
        #pragma unroll
        for (int ji = 0; ji < 8; ++ji) acc[mi][ji] = 0.0f;

    float lin_p[8];
    #pragma unroll
    for (int p = 0; p < 8; ++p) lin_p[p] = 0.0f;

    const float4* emb4 = (const float4*)emb;
    const float4* W1_4 = (const float4*)W1;

    float4 xr[8];
    float4 wr[2];

    // ---- prologue: load tile 0 ----
    #pragma unroll
    for (int p = 0; p < 8; ++p)
        xr[p] = emb4[(size_t)(nbase + p * 16 + ln) * C_DIM + cc];
    wr[0] = W1_4[t];
    wr[1] = W1_4[t + 256];

    __syncthreads();   // WLs ready

    // stage tile 0 into buffer 0
    {
        float* yt = smem;                 // Yt buf 0
        float* ws = smem + 2 * TILE_F;    // Ws buf 0
        const int c0 = cc;                // tile 0 channel
        const float wl0 = WLs[c0], wl1 = WLs[C_DIM + c0], wl2 = WLs[2 * C_DIM + c0];
        #pragma unroll
        for (int p = 0; p < 8; ++p) {
            float4 x = xr[p];
            lin_p[p] = fmaf(x.x, wl0, fmaf(x.y, wl1, fmaf(x.z, wl2, lin_p[p])));
            yt[cc * ROWSTR + p * 16 + ln] = x.w;
        }
        #pragma unroll
        for (int i = 0; i < 2; ++i) {
            int gi = t + 256 * i;
            int k = gi >> 5, g = gi & 31;
            *(float4*)&ws[k * ROWSTR + 4 * (g + (g >> 4))] = wr[i];
        }
    }

    const int wOff = 8 * jg + 4 * (jg >> 3);   // permuted read offset

    for (int ct = 0; ct < NTILES; ++ct) {
        __syncthreads();   // buffer (ct&1) ready for all waves

        // issue next tile's global loads (land during GEMM)
        if (ct < NTILES - 1) {
            #pragma unroll
            for (int p = 0; p < 8; ++p)
                xr[p] = emb4[(size_t)(nbase + p * 16 + ln) * C_DIM + (ct + 1) * KT + cc];
            wr[0] = W1_4[(ct + 1) * 512 + t];
            wr[1] = W1_4[(ct + 1) * 512 + t + 256];
        }

        // GEMM on buffer ct&1
        {
            const float* yt = smem + (ct & 1) * TILE_F;
            const float* ws = smem + (2 + (ct & 1)) * TILE_F;
            #pragma unroll
            for (int k = 0; k < KT; ++k) {
                float4 ya = *(const float4*)&yt[k * ROWSTR + mg * 8];
                float4 yb = *(const float4*)&yt[k * ROWSTR + mg * 8 + 4];
                float4 wa = *(const float4*)&ws[k * ROWSTR + wOff];
                float4 wb = *(const float4*)&ws[k * ROWSTR + wOff + 4];
                float ym[8] = {ya.x, ya.y, ya.z, ya.w, yb.x, yb.y, yb.z, yb.w};
                float wv[8] = {wa.x, wa.y, wa.z, wa.w, wb.x, wb.y, wb.z, wb.w};
                #pragma unroll
                for (int mi = 0; mi < 8; ++mi)
                    #pragma unroll
                    for (int ji = 0; ji < 8; ++ji)
                        acc[mi][ji] = fmaf(ym[mi], wv[ji], acc[mi][ji]);
            }
        }

        // stage next tile into the other buffer (other waves read current buf)
        if (ct < NTILES - 1) {
            float* yt = smem + ((ct + 1) & 1) * TILE_F;
            float* ws = smem + (2 + ((ct + 1) & 1)) * TILE_F;
            const int c0 = (ct + 1) * KT + cc;
            const float wl0 = WLs[c0], wl1 = WLs[C_DIM + c0], wl2 = WLs[2 * C_DIM + c0];
            #pragma unroll
            for (int p = 0; p < 8; ++p) {
                float4 x = xr[p];
                lin_p[p] = fmaf(x.x, wl0, fmaf(x.y, wl1, fmaf(x.z, wl2, lin_p[p])));
                yt[cc * ROWSTR + p * 16 + ln] = x.w;
            }
            #pragma unroll
            for (int i = 0; i < 2; ++i) {
                int gi = t + 256 * i;
                int k = gi >> 5, g = gi & 31;
                *(float4*)&ws[k * ROWSTR + 4 * (g + (g >> 4))] = wr[i];
            }
        }
    }

    // lin reduction: each node's 16 cc-lanes are contiguous lanes
    #pragma unroll
    for (int p = 0; p < 8; ++p) {
        float s = lin_p[p];
        s += __shfl_xor(s, 8);
        s += __shfl_xor(s, 4);
        s += __shfl_xor(s, 2);
        s += __shfl_xor(s, 1);
        if (cc == 0) lin_lds[p * 16 + ln] = s;
    }

    __syncthreads();           // all GEMM reads done -> reuse smem as nl_red
    float* nl_red = smem;      // [m][16] stride 17

    float b1r[8], W2r[8];
    #pragma unroll
    for (int ji = 0; ji < 8; ++ji) {
        int j = 8 * jg + ji;
        b1r[ji] = b1[j];
        W2r[ji] = W2[j];
    }

    #pragma unroll
    for (int mi = 0; mi < 8; ++mi) {
        float s = 0.0f;
        #pragma unroll
        for (int ji = 0; ji < 8; ++ji) {
            float h = acc[mi][ji] + b1r[ji];
            h = h > 0.0f ? h : 0.0f;
            s = fmaf(h, W2r[ji], s);
        }
        nl_red[(mg * 8 + mi) * 17 + jg] = s;
    }
    __syncthreads();

    if (t < M_TILE) {
        float s = lin_lds[t];
        #pragma unroll
        for (int g = 0; g < 16; ++g) s += nl_red[t * 17 + g];
        s += b_lins[0] + b_lins[1] + b_lins[2] + b2[0];
        v_out[nbase + t] = s;
    }
}

// ---------------------------------------------------------------------------
// Kernel 2: one wave per segment; rank sort; quantiles; fused final MLP.
// ---------------------------------------------------------------------------
__global__ __launch_bounds__(256)
void aggregate_kernel(const float* __restrict__ v,
                      const int* __restrict__ batch,
                      const float* __restrict__ Wm1,
                      const float* __restrict__ bm1,
                      const float* __restrict__ Wm2,
                      const float* __restrict__ bm2,
                      float* __restrict__ out)
{
    __shared__ float vals[4][SEGCAP];
    __shared__ float sorted[4][SEGCAP];
    __shared__ float agg_s[4][12];

    const int t    = threadIdx.x;
    const int wid  = t >> 6;
    const int lane = t & 63;
    const int b    = blockIdx.x * 4 + wid;

    int lo = 0, hi = N_NODES;
    while (lo < hi) { int mid = (lo + hi) >> 1; if (batch[mid] < b) lo = mid + 1; else hi = mid; }
    const int start = lo;
    hi = N_NODES;
    while (lo < hi) { int mid = (lo + hi) >> 1; if (batch[mid] <= b) lo = mid + 1; else hi = mid; }
    int cnt = lo - start;
    if (cnt > SEGCAP) cnt = SEGCAP;

    float lsum = 0.0f;
    for (int i = lane; i < cnt; i += 64) {
        float x = v[start + i];
        vals[wid][i] = x;
        lsum += x;
    }
    #pragma unroll
    for (int o = 32; o; o >>= 1) lsum += __shfl_xor(lsum, o);
    __syncthreads();

    for (int i = lane; i < cnt; i += 64) {
        float xi = vals[wid][i];
        int r = 0;
        for (int j = 0; j < cnt; ++j) {
            float xj = vals[wid][j];
            r += (xj < xi) || (xj == xi && j < i);
        }
        sorted[wid][r] = xi;
    }
    __syncthreads();

    if (cnt > 0) {
        float cntf = (float)cnt;
        if (lane == 9)  agg_s[wid][0] = lsum / cntf;
        if (lane == 10) agg_s[wid][1] = sorted[wid][cnt - 1];
        if (lane == 11) agg_s[wid][2] = sorted[wid][0];
        if (lane < 9) {
            float q   = (float)(lane + 1) * 0.1f;
            float pos = q * (cntf - 1.0f);
            float f   = floorf(pos);
            float frac = pos - f;
            int loi = (int)f;
            int hii = loi + 1; if (hii > cnt - 1) hii = cnt - 1;
            agg_s[wid][3 + lane] = sorted[wid][loi] + frac * (sorted[wid][hii] - sorted[wid][loi]);
        }
    } else {
        if (lane < 12) agg_s[wid][lane] = 0.0f;
    }
    __syncthreads();

    float term = 0.0f;
    #pragma unroll
    for (int rj = 0; rj < 2; ++rj) {
        int j = lane + 64 * rj;
        float h = bm1[j];
        #pragma unroll
        for (int k = 0; k < 12; ++k) h = fmaf(agg_s[wid][k], Wm1[k * H_DIM + j], h);
        h = h > 0.0f ? h : 0.0f;
        term = fmaf(h, Wm2[j], term);
    }
    #pragma unroll
    for (int o = 32; o; o >>= 1) term += __shfl_xor(term, o);
    if (lane == 0) out[b] = term + bm2[0];
}

// ---------------------------------------------------------------------------
extern "C" void kernel_launch(void* const* d_in, const int* in_sizes, int n_in,
                              void* d_out, int out_size, void* d_ws, size_t ws_size,
                              hipStream_t stream)
{
    const float* emb    = (const float*)d_in[0];
    const int*   batch  = (const int*)d_in[1];
    const float* W_lins = (const float*)d_in[2];
    const float* b_lins = (const float*)d_in[3];
    const float* W1     = (const float*)d_in[4];
    const float* b1     = (const float*)d_in[5];
    const float* W2     = (const float*)d_in[6];
    const float* b2     = (const float*)d_in[7];
    const float* Wm1    = (const float*)d_in[8];
    const float* bm1    = (const float*)d_in[9];
    const float* Wm2    = (const float*)d_in[10];
    const float* bm2    = (const float*)d_in[11];

    float* out  = (float*)d_out;
    float* vbuf = (float*)d_ws;   // 512 KB scratch

    node_readout_kernel<<<N_NODES / M_TILE, 256, 0, stream>>>(
        emb, W_lins, b_lins, W1, b1, W2, b2, vbuf);
    aggregate_kernel<<<B_SEG / 4, 256, 0, stream>>>(
        vbuf, batch, Wm1, bm1, Wm2, bm2, out);
}

// Round 4
// 430.210 us; speedup vs baseline: 3.5280x; 3.5280x over previous
//
#include <hip/hip_runtime.h>

#define N_NODES 131072
#define C_DIM   128
#define H_DIM   128
#define B_SEG   1024
#define M_TILE  128
#define K_TILE  32
#define YT_STR  132      // Yt row stride: 16B-aligned float4 rows
#define SEGCAP  384

// ---------------------------------------------------------------------------
// Kernel 1: per-node readout  v[n] = lin(n) + relu(x3 @ W1 + b1) @ W2 + b2
// R2 structure + (a) per-block cyclic K-tile rotation to decorrelate the
// load/compute phases of co-resident blocks, (b) W1 tile loaded to regs
// before the X sequence, stored to LDS after it (X loads get the in-flight
// window). No register-array prefetch of X (R3 spill lesson).
// ---------------------------------------------------------------------------
__global__ __launch_bounds__(256, 4)
void node_readout_kernel(const float* __restrict__ emb,
                         const float* __restrict__ W_lins,
                         const float* __restrict__ b_lins,
                         const float* __restrict__ W1,
                         const float* __restrict__ b1,
                         const float* __restrict__ W2,
                         const float* __restrict__ b2,
                         float* __restrict__ v_out)
{
    __shared__ float Yt[K_TILE * YT_STR];     // [cc][m] 16.9 KB
    __shared__ float W1s[K_TILE * H_DIM];     // 16 KB (reused as nl_red)
    __shared__ float WLs[3 * C_DIM];          // 1.5 KB
    __shared__ float lin_lds[M_TILE];         // 0.5 KB

    const int t  = threadIdx.x;
    const int nbase = blockIdx.x * M_TILE;
    const int ln = t >> 5;        // 0..7 : node sub-index per pass
    const int cc = t & 31;        // float4 index within K-tile
    const int jg = t & 15;        // gemm j-group
    const int mg = t >> 4;        // gemm m-group

    for (int i = t; i < 3 * C_DIM; i += 256) WLs[i] = W_lins[i];

    float acc[8][8];
    #pragma unroll
    for (int mi = 0; mi < 8; ++mi)
        #pragma unroll
        for (int ji = 0; ji < 8; ++ji) acc[mi][ji] = 0.0f;

    float lin_p[16];
    #pragma unroll
    for (int p = 0; p < 16; ++p) lin_p[p] = 0.0f;

    const float4* xbase = (const float4*)emb + (size_t)(nbase + ln) * C_DIM;
    const float4* W1_4  = (const float4*)W1;

    // decorrelate barrier phases of co-resident blocks
    const int ct0 = (blockIdx.x ^ (blockIdx.x >> 8)) & 3;

    __syncthreads();   // WLs ready

    for (int it = 0; it < C_DIM / K_TILE; ++it) {
        const int ct = (it + ct0) & 3;
        if (it) __syncthreads();   // previous tile fully consumed

        // (1) issue W1-tile loads into regs (consumed at the end of the phase)
        float4 wr0 = W1_4[ct * 1024 + t];
        float4 wr1 = W1_4[ct * 1024 + t + 256];
        float4 wr2 = W1_4[ct * 1024 + t + 512];
        float4 wr3 = W1_4[ct * 1024 + t + 768];

        // (2) X chunk: pass p covers nodes p*8..p*8+7; 512B contig per half-wave
        {
            const int c0 = ct * K_TILE + cc;
            const float wl0 = WLs[c0], wl1 = WLs[C_DIM + c0], wl2 = WLs[2 * C_DIM + c0];
            #pragma unroll
            for (int p = 0; p < 16; ++p) {
                float4 x = xbase[p * 8 * C_DIM + ct * K_TILE + cc];
                lin_p[p] = fmaf(x.x, wl0, fmaf(x.y, wl1, fmaf(x.z, wl2, lin_p[p])));
                Yt[cc * YT_STR + p * 8 + ln] = x.w;
            }
        }
        // (3) now store W1 tile to LDS (loads have long landed)
        {
            float4* dst = (float4*)W1s;
            dst[t]       = wr0;
            dst[t + 256] = wr1;
            dst[t + 512] = wr2;
            dst[t + 768] = wr3;
        }
        __syncthreads();

        // register-blocked GEMM: 8m x 8j per thread
        #pragma unroll 8
        for (int k = 0; k < K_TILE; ++k) {
            float4 ya = *(const float4*)&Yt[k * YT_STR + mg * 8];
            float4 yb = *(const float4*)&Yt[k * YT_STR + mg * 8 + 4];
            float w[8];
            #pragma unroll
            for (int ji = 0; ji < 8; ++ji) w[ji] = W1s[k * H_DIM + jg + 16 * ji];
            float ym[8] = {ya.x, ya.y, ya.z, ya.w, yb.x, yb.y, yb.z, yb.w};
            #pragma unroll
            for (int mi = 0; mi < 8; ++mi)
                #pragma unroll
                for (int ji = 0; ji < 8; ++ji)
                    acc[mi][ji] = fmaf(ym[mi], w[ji], acc[mi][ji]);
        }
    }

    // reduce lin over the 32 cc lanes
    #pragma unroll
    for (int p = 0; p < 16; ++p) {
        float s = lin_p[p];
        s += __shfl_xor(s, 16);
        s += __shfl_xor(s, 8);
        s += __shfl_xor(s, 4);
        s += __shfl_xor(s, 2);
        s += __shfl_xor(s, 1);
        lin_p[p] = s;
    }
    if (cc == 0) {
        #pragma unroll
        for (int p = 0; p < 16; ++p) lin_lds[p * 8 + ln] = lin_p[p];
    }

    __syncthreads();                // GEMM reads done -> reuse W1s as nl_red
    float* nl_red = W1s;            // [m][jg] stride 17

    float b1r[8], W2r[8];
    #pragma unroll
    for (int ji = 0; ji < 8; ++ji) {
        int j = jg + 16 * ji;
        b1r[ji] = b1[j];
        W2r[ji] = W2[j];
    }

    #pragma unroll
    for (int mi = 0; mi < 8; ++mi) {
        float s = 0.0f;
        #pragma unroll
        for (int ji = 0; ji < 8; ++ji) {
            float h = acc[mi][ji] + b1r[ji];
            h = h > 0.0f ? h : 0.0f;
            s = fmaf(h, W2r[ji], s);
        }
        nl_red[(mg * 8 + mi) * 17 + jg] = s;
    }
    __syncthreads();

    if (t < M_TILE) {
        float s = lin_lds[t];
        #pragma unroll
        for (int g = 0; g < 16; ++g) s += nl_red[t * 17 + g];
        s += b_lins[0] + b_lins[1] + b_lins[2] + b2[0];
        v_out[nbase + t] = s;
    }
}

// ---------------------------------------------------------------------------
// Kernel 2: one wave per segment; rank sort; quantiles; fused final MLP.
// ---------------------------------------------------------------------------
__global__ __launch_bounds__(256)
void aggregate_kernel(const float* __restrict__ v,
                      const int* __restrict__ batch,
                      const float* __restrict__ Wm1,
                      const float* __restrict__ bm1,
                      const float* __restrict__ Wm2,
                      const float* __restrict__ bm2,
                      float* __restrict__ out)
{
    __shared__ float vals[4][SEGCAP];
    __shared__ float sorted[4][SEGCAP];
    __shared__ float agg_s[4][12];

    const int t    = threadIdx.x;
    const int wid  = t >> 6;
    const int lane = t & 63;
    const int b    = blockIdx.x * 4 + wid;

    int lo = 0, hi = N_NODES;
    while (lo < hi) { int mid = (lo + hi) >> 1; if (batch[mid] < b) lo = mid + 1; else hi = mid; }
    const int start = lo;
    hi = N_NODES;
    while (lo < hi) { int mid = (lo + hi) >> 1; if (batch[mid] <= b) lo = mid + 1; else hi = mid; }
    int cnt = lo - start;
    if (cnt > SEGCAP) cnt = SEGCAP;

    float lsum = 0.0f;
    for (int i = lane; i < cnt; i += 64) {
        float x = v[start + i];
        vals[wid][i] = x;
        lsum += x;
    }
    #pragma unroll
    for (int o = 32; o; o >>= 1) lsum += __shfl_xor(lsum, o);
    __syncthreads();

    for (int i = lane; i < cnt; i += 64) {
        float xi = vals[wid][i];
        int r = 0;
        for (int j = 0; j < cnt; ++j) {
            float xj = vals[wid][j];
            r += (xj < xi) || (xj == xi && j < i);
        }
        sorted[wid][r] = xi;
    }
    __syncthreads();

    if (cnt > 0) {
        float cntf = (float)cnt;
        if (lane == 9)  agg_s[wid][0] = lsum / cntf;
        if (lane == 10) agg_s[wid][1] = sorted[wid][cnt - 1];
        if (lane == 11) agg_s[wid][2] = sorted[wid][0];
        if (lane < 9) {
            float q   = (float)(lane + 1) * 0.1f;
            float pos = q * (cntf - 1.0f);
            float f   = floorf(pos);
            float frac = pos - f;
            int loi = (int)f;
            int hii = loi + 1; if (hii > cnt - 1) hii = cnt - 1;
            agg_s[wid][3 + lane] = sorted[wid][loi] + frac * (sorted[wid][hii] - sorted[wid][loi]);
        }
    } else {
        if (lane < 12) agg_s[wid][lane] = 0.0f;
    }
    __syncthreads();

    float term = 0.0f;
    #pragma unroll
    for (int rj = 0; rj < 2; ++rj) {
        int j = lane + 64 * rj;
        float h = bm1[j];
        #pragma unroll
        for (int k = 0; k < 12; ++k) h = fmaf(agg_s[wid][k], Wm1[k * H_DIM + j], h);
        h = h > 0.0f ? h : 0.0f;
        term = fmaf(h, Wm2[j], term);
    }
    #pragma unroll
    for (int o = 32; o; o >>= 1) term += __shfl_xor(term, o);
    if (lane == 0) out[b] = term + bm2[0];
}

// ---------------------------------------------------------------------------
extern "C" void kernel_launch(void* const* d_in, const int* in_sizes, int n_in,
                              void* d_out, int out_size, void* d_ws, size_t ws_size,
                              hipStream_t stream)
{
    const float* emb    = (const float*)d_in[0];
    const int*   batch  = (const int*)d_in[1];
    const float* W_lins = (const float*)d_in[2];
    const float* b_lins = (const float*)d_in[3];
    const float* W1     = (const float*)d_in[4];
    const float* b1     = (const float*)d_in[5];
    const float* W2     = (const float*)d_in[6];
    const float* b2     = (const float*)d_in[7];
    const float* Wm1    = (const float*)d_in[8];
    const float* bm1    = (const float*)d_in[9];
    const float* Wm2    = (const float*)d_in[10];
    const float* bm2    = (const float*)d_in[11];

    float* out  = (float*)d_out;
    float* vbuf = (float*)d_ws;   // 512 KB scratch

    node_readout_kernel<<<N_NODES / M_TILE, 256, 0, stream>>>(
        emb, W_lins, b_lins, W1, b1, W2, b2, vbuf);
    aggregate_kernel<<<B_SEG / 4, 256, 0, stream>>>(
        vbuf, batch, Wm1, bm1, Wm2, bm2, out);
}